// Round 2
// 1056.168 us; speedup vs baseline: 1.0605x; 1.0605x over previous
//
#include <hip/hip_runtime.h>

#define FEAT 64
#define N_DATA 542080
#define N_TRUNC 40320
#define NB_TOTAL (N_TRUNC + N_DATA)          // 582400 combined row-buckets
#define SCAN_TILE 4096                       // elements per scan block (256 thr x 16)

typedef float nfloat4 __attribute__((ext_vector_type(4)));  // native vec for NT stores

// ---------------- Combined CSR build ----------------
// Buckets: [0, N_TRUNC) = down-phase dst rows, [N_TRUNC, NB_TOTAL) = up-phase dst rows.
// One offsets array (NB_TOTAL+1) and one csr pair array (e_down + e_up) serve both phases.

__global__ void histogram_both(const int* __restrict__ ddst, int e_down,
                               const int* __restrict__ udst, int e_up,
                               int* __restrict__ counts) {
    int e = blockIdx.x * blockDim.x + threadIdx.x;
    if (e < e_down) {
        atomicAdd(&counts[ddst[e]], 1);
    } else if (e < e_down + e_up) {
        atomicAdd(&counts[N_TRUNC + udst[e - e_down]], 1);
    }
}

__global__ void scan_block_sums(const int* __restrict__ counts, int n,
                                int* __restrict__ blockSums) {
    __shared__ int lds[256];
    int tid = threadIdx.x;
    int base = blockIdx.x * SCAN_TILE + tid * 16;
    int s = 0;
    #pragma unroll
    for (int i = 0; i < 16; ++i) {
        int idx = base + i;
        s += (idx < n) ? counts[idx] : 0;
    }
    lds[tid] = s;
    __syncthreads();
    for (int off = 128; off > 0; off >>= 1) {
        if (tid < off) lds[tid] += lds[tid + off];
        __syncthreads();
    }
    if (tid == 0) blockSums[blockIdx.x] = lds[0];
}

// Single 256-thread block: exclusive scan of up to 256 block sums (nblk = 143).
__global__ void scan_sums_block(int* __restrict__ blockSums, int nblocks) {
    __shared__ int lds[256];
    int tid = threadIdx.x;
    lds[tid] = (tid < nblocks) ? blockSums[tid] : 0;
    __syncthreads();
    for (int off = 1; off < 256; off <<= 1) {
        int v = (tid >= off) ? lds[tid - off] : 0;
        __syncthreads();
        if (tid >= off) lds[tid] += v;
        __syncthreads();
    }
    if (tid < nblocks) blockSums[tid] = (tid == 0) ? 0 : lds[tid - 1];
}

// Writes exclusive offsets AND zeroes counts in place (counts becomes the build cursor).
__global__ void scan_write_offsets(int* __restrict__ counts, int n,
                                   const int* __restrict__ blockSums,
                                   int* __restrict__ offsets, int total_edges) {
    __shared__ int lds[256];
    int tid = threadIdx.x;
    int base = blockIdx.x * SCAN_TILE + tid * 16;
    int local[16];
    int s = 0;
    #pragma unroll
    for (int i = 0; i < 16; ++i) {
        int idx = base + i;
        int v = (idx < n) ? counts[idx] : 0;
        local[i] = s;           // exclusive within thread
        s += v;
    }
    lds[tid] = s;
    __syncthreads();
    for (int off = 1; off < 256; off <<= 1) {
        int v = (tid >= off) ? lds[tid - off] : 0;
        __syncthreads();
        if (tid >= off) lds[tid] += v;
        __syncthreads();
    }
    int threadOffset = (tid == 0) ? 0 : lds[tid - 1];
    int blockOffset = blockSums[blockIdx.x];
    #pragma unroll
    for (int i = 0; i < 16; ++i) {
        int idx = base + i;
        if (idx < n) {
            offsets[idx] = blockOffset + threadOffset + local[i];
            counts[idx] = 0;    // reset for use as build cursor
        }
    }
    if (blockIdx.x == 0 && tid == 0) offsets[n] = total_edges;
}

__global__ void build_csr_both(const int* __restrict__ dsrc, const int* __restrict__ ddst,
                               const float* __restrict__ dw, int e_down,
                               const int* __restrict__ usrc, const int* __restrict__ udst,
                               const float* __restrict__ uw, int e_up,
                               const int* __restrict__ offsets, int* __restrict__ cursor,
                               int2* __restrict__ csr_pair) {
    int e = blockIdx.x * blockDim.x + threadIdx.x;
    int n = e_down + e_up;
    if (e >= n) return;
    int s, b; float wv;
    if (e < e_down) {
        s = dsrc[e]; b = ddst[e]; wv = dw[e];
    } else {
        int k = e - e_down;
        s = usrc[k]; b = N_TRUNC + udst[k]; wv = uw[k];
    }
    int pos = offsets[b] + atomicAdd(&cursor[b], 1);
    int2 p;
    p.x = s;
    p.y = __float_as_int(wv);
    csr_pair[pos] = p;
}

// ---------------- Gather kernel ----------------
// 16 threads per output row; each thread owns one float4 feature chunk and
// accumulates BOTH batches in registers. 2x edge unroll for load-level
// parallelism; NT template streams the stores (used for the 277 MB out write).
template <bool NT>
__global__ __launch_bounds__(256) void sparse_gather(
    const float* __restrict__ h, size_t h_bstride,
    float* __restrict__ out, size_t out_bstride,
    const int* __restrict__ offsets,
    const int2* __restrict__ csr_pair,
    int n_out)
{
    int id = blockIdx.x * blockDim.x + threadIdx.x;
    int d = id >> 4;
    int c = (id & 15) * 4;
    if (d >= n_out) return;

    int beg = offsets[d];
    int end = offsets[d + 1];

    float4 acc0 = make_float4(0.f, 0.f, 0.f, 0.f);
    float4 acc1 = make_float4(0.f, 0.f, 0.f, 0.f);

    const float* hc = h + c;
    int p = beg;
    for (; p + 2 <= end; p += 2) {
        int2 pa = csr_pair[p];
        int2 pb = csr_pair[p + 1];
        float wa = __int_as_float(pa.y);
        float wb = __int_as_float(pb.y);
        const float* ra0 = hc + (size_t)pa.x * FEAT;
        const float* rb0 = hc + (size_t)pb.x * FEAT;
        float4 va0 = *reinterpret_cast<const float4*>(ra0);
        float4 vb0 = *reinterpret_cast<const float4*>(rb0);
        float4 va1 = *reinterpret_cast<const float4*>(ra0 + h_bstride);
        float4 vb1 = *reinterpret_cast<const float4*>(rb0 + h_bstride);
        acc0.x += wa * va0.x; acc0.y += wa * va0.y;
        acc0.z += wa * va0.z; acc0.w += wa * va0.w;
        acc1.x += wa * va1.x; acc1.y += wa * va1.y;
        acc1.z += wa * va1.z; acc1.w += wa * va1.w;
        acc0.x += wb * vb0.x; acc0.y += wb * vb0.y;
        acc0.z += wb * vb0.z; acc0.w += wb * vb0.w;
        acc1.x += wb * vb1.x; acc1.y += wb * vb1.y;
        acc1.z += wb * vb1.z; acc1.w += wb * vb1.w;
    }
    if (p < end) {
        int2 pr = csr_pair[p];
        float ww = __int_as_float(pr.y);
        const float* r0 = hc + (size_t)pr.x * FEAT;
        float4 v0 = *reinterpret_cast<const float4*>(r0);
        float4 v1 = *reinterpret_cast<const float4*>(r0 + h_bstride);
        acc0.x += ww * v0.x; acc0.y += ww * v0.y;
        acc0.z += ww * v0.z; acc0.w += ww * v0.w;
        acc1.x += ww * v1.x; acc1.y += ww * v1.y;
        acc1.z += ww * v1.z; acc1.w += ww * v1.w;
    }

    float* o0 = out + (size_t)d * FEAT + c;
    if (NT) {
        nfloat4 n0 = { acc0.x, acc0.y, acc0.z, acc0.w };
        nfloat4 n1 = { acc1.x, acc1.y, acc1.z, acc1.w };
        __builtin_nontemporal_store(n0, reinterpret_cast<nfloat4*>(o0));
        __builtin_nontemporal_store(n1, reinterpret_cast<nfloat4*>(o0 + out_bstride));
    } else {
        *reinterpret_cast<float4*>(o0) = acc0;
        *reinterpret_cast<float4*>(o0 + out_bstride) = acc1;
    }
}

// ---------------- Fallback atomic kernel (ws too small) ----------------
__global__ __launch_bounds__(256) void sparse_project_atomic(
    const float* __restrict__ h, size_t h_bstride,
    float* __restrict__ out, size_t out_bstride,
    const int* __restrict__ src, const int* __restrict__ dst,
    const float* __restrict__ w, int n_edges)
{
    int id = blockIdx.x * blockDim.x + threadIdx.x;
    int e = id >> 4;
    int c = (id & 15) * 4;
    if (e >= n_edges) return;
    int b = blockIdx.y;
    const float* hb = h + (size_t)b * h_bstride;
    float*       ob = out + (size_t)b * out_bstride;
    int   s  = src[e];
    int   d  = dst[e];
    float ww = w[e];
    const float4 v = *reinterpret_cast<const float4*>(hb + (size_t)s * FEAT + c);
    float* op = ob + (size_t)d * FEAT + c;
    atomicAdd(op + 0, ww * v.x);
    atomicAdd(op + 1, ww * v.y);
    atomicAdd(op + 2, ww * v.z);
    atomicAdd(op + 3, ww * v.w);
}

static inline size_t align16(size_t v) { return (v + 15) & ~(size_t)15; }

extern "C" void kernel_launch(void* const* d_in, const int* in_sizes, int n_in,
                              void* d_out, int out_size, void* d_ws, size_t ws_size,
                              hipStream_t stream) {
    const float* x        = (const float*)d_in[0];   // (2, 2, 1, N_DATA, F)
    const int*   down_src = (const int*)d_in[1];
    const int*   down_dst = (const int*)d_in[2];
    const float* down_w   = (const float*)d_in[3];
    const int*   up_src   = (const int*)d_in[4];
    const int*   up_dst   = (const int*)d_in[5];
    const float* up_w     = (const float*)d_in[6];
    float* out = (float*)d_out;

    const int e_down  = in_sizes[1];
    const int e_up    = in_sizes[4];
    const int e_total = e_down + e_up;

    // x[:, -1] slice: batch b lives at x + (2b+1)*N_DATA*FEAT
    const float* x_last = x + (size_t)N_DATA * FEAT;
    const size_t x_bstride = (size_t)2 * N_DATA * FEAT;

    // ---- workspace layout ----
    char* ws = (char*)d_ws;
    size_t off = 0;
    float* h_trunc   = (float*)(ws + off); off += align16((size_t)2 * N_TRUNC * FEAT * 4);
    int*   offsets   = (int*)(ws + off);   off += align16(((size_t)NB_TOTAL + 1) * 4);
    int*   counts    = (int*)(ws + off);   off += align16((size_t)NB_TOTAL * 4);
    int2*  csr_all   = (int2*)(ws + off);  off += align16((size_t)e_total * 8);
    int*   blockSums = (int*)(ws + off);   off += align16(1024);
    const size_t needed = off;

    if (ws_size < needed) {
        // Fallback: atomic scatter path (needs only h_trunc)
        hipMemsetAsync(h_trunc, 0, (size_t)2 * N_TRUNC * FEAT * 4, stream);
        hipMemsetAsync(out, 0, (size_t)out_size * sizeof(float), stream);
        dim3 g1((e_down * 16 + 255) / 256, 2);
        sparse_project_atomic<<<g1, 256, 0, stream>>>(
            x_last, x_bstride, h_trunc, (size_t)N_TRUNC * FEAT,
            down_src, down_dst, down_w, e_down);
        dim3 g2((e_up * 16 + 255) / 256, 2);
        sparse_project_atomic<<<g2, 256, 0, stream>>>(
            h_trunc, (size_t)N_TRUNC * FEAT, out, (size_t)N_DATA * FEAT,
            up_src, up_dst, up_w, e_up);
        return;
    }

    const int nblk = (NB_TOTAL + SCAN_TILE - 1) / SCAN_TILE;   // 143 <= 256

    // ---- combined CSR build: 6 dispatches total ----
    hipMemsetAsync(counts, 0, (size_t)NB_TOTAL * 4, stream);
    histogram_both<<<(e_total + 255) / 256, 256, 0, stream>>>(
        down_dst, e_down, up_dst, e_up, counts);
    scan_block_sums<<<nblk, 256, 0, stream>>>(counts, NB_TOTAL, blockSums);
    scan_sums_block<<<1, 256, 0, stream>>>(blockSums, nblk);
    scan_write_offsets<<<nblk, 256, 0, stream>>>(counts, NB_TOTAL, blockSums, offsets, e_total);
    build_csr_both<<<(e_total + 255) / 256, 256, 0, stream>>>(
        down_src, down_dst, down_w, e_down,
        up_src, up_dst, up_w, e_up,
        offsets, counts, csr_all);

    // ---- down gather: x[:, -1] -> h_trunc (both batches per thread) ----
    {
        int threads = N_TRUNC * 16;
        sparse_gather<false><<<(threads + 255) / 256, 256, 0, stream>>>(
            x_last, x_bstride,
            h_trunc, (size_t)N_TRUNC * FEAT,
            offsets, csr_all, N_TRUNC);
    }
    // ---- up gather: h_trunc -> out (streaming stores, 277 MB write-once) ----
    {
        int threads = N_DATA * 16;
        sparse_gather<true><<<(threads + 255) / 256, 256, 0, stream>>>(
            h_trunc, (size_t)N_TRUNC * FEAT,
            out, (size_t)N_DATA * FEAT,
            offsets + N_TRUNC, csr_all, N_DATA);
    }
}